// Round 1
// baseline (340.765 us; speedup 1.0000x reference)
//
#include <hip/hip_runtime.h>
#include <hip/hip_bf16.h>
#include <hip/hip_fp16.h>

#define UNITS 512
#define D_DEC 1024
#define D_ENC 1024
#define BATCH 32
#define S_LEN 2048

typedef _Float16 f16x8 __attribute__((ext_vector_type(8)));
typedef _Float16 f16x4 __attribute__((ext_vector_type(4)));
typedef float f32x4 __attribute__((ext_vector_type(4)));

// ---------------- prep: transpose + convert W2 [1024][512] f32 -> W2h [512][1024] f16
__global__ __launch_bounds__(256) void k_prep_w2(const float* __restrict__ W2,
                                                 _Float16* __restrict__ W2h) {
    __shared__ float tile[32][33];
    const int kb = blockIdx.x * 32;
    const int nb = blockIdx.y * 32;
    const int tx = threadIdx.x;   // 0..31
    const int ty = threadIdx.y;   // 0..7
    for (int i = 0; i < 32; i += 8)
        tile[ty + i][tx] = W2[(size_t)(kb + ty + i) * UNITS + nb + tx];
    __syncthreads();
    for (int i = 0; i < 32; i += 8)
        W2h[(size_t)(nb + ty + i) * D_DEC + kb + tx] = (_Float16)tile[tx][ty + i];
}

// ---------------- prep: query[b][u] = dec[b] @ W1[:,u] + b1[u]   (fp32, exact-ish)
__global__ __launch_bounds__(512) void k_query(const float* __restrict__ dec,
                                               const float* __restrict__ W1,
                                               const float* __restrict__ b1,
                                               float* __restrict__ query) {
    const int b = blockIdx.x;
    const int u = threadIdx.x;  // 0..511
    __shared__ float dl[D_DEC];
    for (int d = threadIdx.x; d < D_DEC; d += 512) dl[d] = dec[(size_t)b * D_DEC + d];
    __syncthreads();
    float acc = b1[u];
    for (int d = 0; d < D_DEC; ++d) acc += dl[d] * W1[(size_t)d * UNITS + u];
    query[(size_t)b * UNITS + u] = acc;
}

// ---------------- main: scores[m] = sum_u tanh(enc[m]@W2[:,u] + query[b][u] + b2[u]) * V[u] + bv
// GEMM M=65536 K=1024 N=512, f16 MFMA 16x16x32, tile 64x512, BK=32, 8 waves.
#define BM 64
#define BK 32
#define NWAVES 8

__global__ __launch_bounds__(512) void k_scores(const float* __restrict__ enc,
                                                const _Float16* __restrict__ W2h,
                                                const float* __restrict__ query,
                                                const float* __restrict__ b2,
                                                const float* __restrict__ V,
                                                const float* __restrict__ bv,
                                                float* __restrict__ scores) {
    __shared__ _Float16 Ab[BM][BK + 8];      // 64 x 40 f16 = 5120 B (pad -> 2-way max)
    __shared__ _Float16 Bb[UNITS][BK + 8];   // 512 x 40 f16 = 40960 B
    __shared__ float sc_part[NWAVES][BM];    // 2 KB

    const int tid  = threadIdx.x;
    const int lane = tid & 63;
    const int wave = tid >> 6;           // 0..7, owns cols [wave*64, wave*64+64)
    const int row0 = blockIdx.x * BM;    // global M row
    const int b    = row0 / S_LEN;       // BM divides S -> block within one batch

    f32x4 acc[4][4];
    for (int i = 0; i < 4; ++i)
        for (int j = 0; j < 4; ++j) acc[i][j] = (f32x4){0.f, 0.f, 0.f, 0.f};

    const int g = lane >> 4;   // 0..3  (k-group)
    const int r = lane & 15;   // 0..15 (row/col within fragment)

    for (int k0 = 0; k0 < D_DEC; k0 += BK) {
        // stage A: 64 rows x 32 k, fp32 -> f16. 512 threads, 1 float4 each.
        {
            const int m  = tid >> 3;
            const int kg = (tid & 7) * 4;
            const float4 v = *reinterpret_cast<const float4*>(
                &enc[(size_t)(row0 + m) * D_ENC + k0 + kg]);
            f16x4 h = {(_Float16)v.x, (_Float16)v.y, (_Float16)v.z, (_Float16)v.w};
            *reinterpret_cast<f16x4*>(&Ab[m][kg]) = h;
        }
        // stage B: 512 n x 32 k f16 from pre-transposed W2h. 4 x 16B per thread.
        for (int c = tid; c < UNITS * 4; c += 512) {
            const int n  = c >> 2;
            const int kc = (c & 3) * 8;
            f16x8 v = *reinterpret_cast<const f16x8*>(&W2h[(size_t)n * D_DEC + k0 + kc]);
            *reinterpret_cast<f16x8*>(&Bb[n][kc]) = v;
        }
        __syncthreads();

        f16x8 afrag[4], bfrag[4];
        for (int fr = 0; fr < 4; ++fr)
            afrag[fr] = *reinterpret_cast<const f16x8*>(&Ab[fr * 16 + r][g * 8]);
        for (int fc = 0; fc < 4; ++fc)
            bfrag[fc] = *reinterpret_cast<const f16x8*>(&Bb[wave * 64 + fc * 16 + r][g * 8]);
        for (int fr = 0; fr < 4; ++fr)
            for (int fc = 0; fc < 4; ++fc)
                acc[fr][fc] = __builtin_amdgcn_mfma_f32_16x16x32_f16(
                    afrag[fr], bfrag[fc], acc[fr][fc], 0, 0, 0);
        __syncthreads();
    }

    // epilogue: tanh(values + query + b2) * V, reduce over N
    float psum[4][4];
    for (int fr = 0; fr < 4; ++fr)
        for (int i = 0; i < 4; ++i) psum[fr][i] = 0.f;

    for (int fc = 0; fc < 4; ++fc) {
        const int col = wave * 64 + fc * 16 + r;
        const float qb = query[(size_t)b * UNITS + col] + b2[col];
        const float vv = V[col];
        for (int fr = 0; fr < 4; ++fr)
            for (int i = 0; i < 4; ++i) {
                const float t = tanhf(acc[fr][fc][i] + qb);
                psum[fr][i] += t * vv;
            }
    }
    // reduce across the 16 lanes (r) of each k-group
    for (int off = 1; off < 16; off <<= 1)
        for (int fr = 0; fr < 4; ++fr)
            for (int i = 0; i < 4; ++i)
                psum[fr][i] += __shfl_xor(psum[fr][i], off, 64);
    if (r == 0)
        for (int fr = 0; fr < 4; ++fr)
            for (int i = 0; i < 4; ++i)
                sc_part[wave][fr * 16 + g * 4 + i] = psum[fr][i];
    __syncthreads();
    if (tid < BM) {
        float s = bv[0];
        for (int w = 0; w < NWAVES; ++w) s += sc_part[w][tid];
        scores[(size_t)row0 + tid] = s;
    }
}

// ---------------- softmax over S per batch
__global__ __launch_bounds__(256) void k_softmax(const float* __restrict__ scores,
                                                 float* __restrict__ weights) {
    const int b = blockIdx.x;
    const int tid = threadIdx.x;
    const float* s = scores + (size_t)b * S_LEN;
    __shared__ float wmax[4], wsum[4];
    float v[8];
    float lm = -1e30f;
    for (int i = 0; i < 8; ++i) { v[i] = s[tid + i * 256]; lm = fmaxf(lm, v[i]); }
    for (int off = 32; off; off >>= 1) lm = fmaxf(lm, __shfl_xor(lm, off, 64));
    if ((tid & 63) == 0) wmax[tid >> 6] = lm;
    __syncthreads();
    const float m = fmaxf(fmaxf(wmax[0], wmax[1]), fmaxf(wmax[2], wmax[3]));
    float ls = 0.f;
    for (int i = 0; i < 8; ++i) { v[i] = expf(v[i] - m); ls += v[i]; }
    for (int off = 32; off; off >>= 1) ls += __shfl_xor(ls, off, 64);
    if ((tid & 63) == 0) wsum[tid >> 6] = ls;
    __syncthreads();
    const float inv = 1.f / (wsum[0] + wsum[1] + wsum[2] + wsum[3]);
    for (int i = 0; i < 8; ++i)
        weights[(size_t)b * S_LEN + tid + i * 256] = v[i] * inv;
}

// ---------------- context partials: part[b,ch][d] = sum_{s in chunk} w[s] * enc[b][s][d]
#define SCH 128
#define NCH (S_LEN / SCH)   // 16
__global__ __launch_bounds__(256) void k_ctx_part(const float* __restrict__ enc,
                                                  const float* __restrict__ weights,
                                                  float* __restrict__ part) {
    const int b  = blockIdx.x >> 4;
    const int ch = blockIdx.x & 15;
    const int s0 = ch * SCH;
    const int d4 = threadIdx.x * 4;
    __shared__ float wl[SCH];
    if (threadIdx.x < SCH) wl[threadIdx.x] = weights[(size_t)b * S_LEN + s0 + threadIdx.x];
    __syncthreads();
    float4 a = {0.f, 0.f, 0.f, 0.f};
    const float* base = enc + (size_t)b * S_LEN * D_ENC + (size_t)s0 * D_ENC + d4;
    for (int s = 0; s < SCH; ++s) {
        const float4 e = *reinterpret_cast<const float4*>(base + (size_t)s * D_ENC);
        const float w = wl[s];
        a.x += w * e.x; a.y += w * e.y; a.z += w * e.z; a.w += w * e.w;
    }
    *reinterpret_cast<float4*>(&part[(size_t)blockIdx.x * D_ENC + d4]) = a;
}

__global__ __launch_bounds__(256) void k_ctx_combine(const float* __restrict__ part,
                                                     float* __restrict__ ctx) {
    const int idx = blockIdx.x * 256 + threadIdx.x;  // 0..32767
    const int b = idx >> 10;
    const int d = idx & 1023;
    float s = 0.f;
    for (int c = 0; c < NCH; ++c) s += part[(size_t)(b * NCH + c) * D_ENC + d];
    ctx[idx] = s;
}

extern "C" void kernel_launch(void* const* d_in, const int* in_sizes, int n_in,
                              void* d_out, int out_size, void* d_ws, size_t ws_size,
                              hipStream_t stream) {
    const float* dec = (const float*)d_in[0];   // [32,1,1024]
    const float* enc = (const float*)d_in[1];   // [32,2048,1024]
    const float* W1  = (const float*)d_in[2];   // [1024,512]
    const float* b1  = (const float*)d_in[3];   // [512]
    const float* W2  = (const float*)d_in[4];   // [1024,512]
    const float* b2  = (const float*)d_in[5];   // [512]
    const float* V   = (const float*)d_in[6];   // [512,1]
    const float* bv  = (const float*)d_in[7];   // [1]

    float* out = (float*)d_out;
    float* out_ctx = out;                 // [32,1024]
    float* out_w   = out + BATCH * D_ENC; // [32,2048]

    char* ws = (char*)d_ws;
    _Float16* W2h  = (_Float16*)(ws);                       // 1 MB
    float* query   = (float*)(ws + (1 << 20));              // 64 KB
    float* scores  = (float*)(ws + (1 << 20) + (1 << 16));  // 256 KB
    float* part    = (float*)(ws + (1 << 20) + (1 << 16) + (1 << 18)); // 2 MB

    k_prep_w2<<<dim3(D_DEC / 32, UNITS / 32), dim3(32, 8), 0, stream>>>(W2, W2h);
    k_query<<<BATCH, 512, 0, stream>>>(dec, W1, b1, query);
    k_scores<<<(BATCH * S_LEN) / BM, 512, 0, stream>>>(enc, W2h, query, b2, V, bv, scores);
    k_softmax<<<BATCH, 256, 0, stream>>>(scores, out_w);
    k_ctx_part<<<BATCH * NCH, 256, 0, stream>>>(enc, out_w, part);
    k_ctx_combine<<<(BATCH * D_ENC) / 256, 256, 0, stream>>>(part, out_ctx);
}

// Round 2
// 245.319 us; speedup vs baseline: 1.3891x; 1.3891x over previous
//
#include <hip/hip_runtime.h>
#include <hip/hip_bf16.h>
#include <hip/hip_fp16.h>

#define UNITS 512
#define D_DEC 1024
#define D_ENC 1024
#define BATCH 32
#define S_LEN 2048

typedef _Float16 f16x8 __attribute__((ext_vector_type(8)));
typedef float f32x4 __attribute__((ext_vector_type(4)));

__device__ inline float tanh_fast(float x) {
    // tanh(x) = 1 - 2/(e^{2x}+1); exact limits at +-inf
    float e = __expf(2.f * x);
    return 1.f - 2.f * __builtin_amdgcn_rcpf(e + 1.f);
}

// ---------------- prep: transpose + convert W2 [1024][512] f32 -> W2h [512][1024] f16
__global__ __launch_bounds__(256) void k_prep_w2(const float* __restrict__ W2,
                                                 _Float16* __restrict__ W2h) {
    __shared__ float tile[32][33];
    const int kb = blockIdx.x * 32;
    const int nb = blockIdx.y * 32;
    const int tx = threadIdx.x;   // 0..31
    const int ty = threadIdx.y;   // 0..7
    for (int i = 0; i < 32; i += 8)
        tile[ty + i][tx] = W2[(size_t)(kb + ty + i) * UNITS + nb + tx];
    __syncthreads();
    for (int i = 0; i < 32; i += 8)
        W2h[(size_t)(nb + ty + i) * D_DEC + kb + tx] = (_Float16)tile[tx][ty + i];
}

// ---------------- prep: query[b][u] = dec[b] @ W1[:,u] + b1[u]
__global__ __launch_bounds__(512) void k_query(const float* __restrict__ dec,
                                               const float* __restrict__ W1,
                                               const float* __restrict__ b1,
                                               float* __restrict__ query) {
    const int b = blockIdx.x;
    const int u = threadIdx.x;  // 0..511
    __shared__ float dl[D_DEC];
    for (int d = threadIdx.x; d < D_DEC; d += 512) dl[d] = dec[(size_t)b * D_DEC + d];
    __syncthreads();
    float acc = b1[u];
    for (int d = 0; d < D_DEC; ++d) acc += dl[d] * W1[(size_t)d * UNITS + u];
    query[(size_t)b * UNITS + u] = acc;
}

// ---------------- scores GEMM: M=65536 K=1024, per block: 128 rows x 128 cols,
// 4 waves (2x2) of 64x64, BK=64, f16 MFMA 16x16x32.
// psc[n_blk][row] = sum over block's 128 cols of tanh(value+query+b2)*V
#define BM 128
#define BKK 64

__global__ __launch_bounds__(256, 2) void k_scores(const float* __restrict__ enc,
                                                   const _Float16* __restrict__ W2h,
                                                   const float* __restrict__ query,
                                                   const float* __restrict__ b2,
                                                   const float* __restrict__ V,
                                                   float* __restrict__ psc) {
    __shared__ __align__(16) _Float16 Ab[BM][72];        // padded: conflict-free
    __shared__ __align__(16) _Float16 Bb[BM * BKK];      // linear, XOR-swizzled content
    __shared__ float sc_part[2][BM];

    const int tid  = threadIdx.x;
    const int lane = tid & 63;
    const int w    = tid >> 6;        // 0..3
    const int wr   = w >> 1;          // row-half of block
    const int wc   = w & 1;           // col-half of block
    const int g    = lane >> 4;       // 0..3 k-group
    const int r    = lane & 15;       // 0..15

    // grid swizzle: 4 n-blocks of one m-panel land on the same XCD (b%8)
    const unsigned b = blockIdx.x;
    const int m_blk = (int)(((b >> 5) << 3) | (b & 7));   // 0..511
    const int n_blk = (int)((b >> 3) & 3);                // 0..3
    const int row0  = m_blk * BM;
    const int n0    = n_blk * 128;
    const int bat   = row0 >> 11;     // row0 / 2048

    f32x4 acc[4][4];
#pragma unroll
    for (int i = 0; i < 4; ++i)
#pragma unroll
        for (int j = 0; j < 4; ++j) acc[i][j] = (f32x4){0.f, 0.f, 0.f, 0.f};

    // A staging geometry: thread -> row am, k-half ak (32 fp32)
    const int am = tid >> 1;
    const int ak = (tid & 1) * 32;
    const float* aptr = enc + (size_t)(row0 + am) * D_ENC + ak;

    for (int k0 = 0; k0 < D_DEC; k0 += BKK) {
        // ---- B stage: 16 KB via global_load_lds, source pre-swizzled so the
        // linear LDS image holds row n with k-bytes XORed by ((n&7)<<4).
#pragma unroll
        for (int i = 0; i < 4; ++i) {
            const int g16 = i * 256 + tid;          // 16B granule index in tile
            const int n   = g16 >> 3;               // 0..127 LDS row
            const int kb  = (g16 & 7) * 16;         // byte offset in row
            const int ksrc = (kb ^ ((n & 7) << 4)) >> 1;  // f16 element offset
            const _Float16* src = W2h + (size_t)(n0 + n) * D_DEC + k0 + ksrc;
            _Float16* dst = &Bb[g16 * 8];
            __builtin_amdgcn_global_load_lds(
                (const __attribute__((address_space(1))) void*)src,
                (__attribute__((address_space(3))) void*)dst, 16, 0, 0);
        }
        // ---- A stage: 8x float4 fp32 -> f16, 4x ds_write_b128 (padded rows)
        {
            const float* ap = aptr + k0;
            float4 c[8];
#pragma unroll
            for (int i = 0; i < 8; ++i)
                c[i] = *reinterpret_cast<const float4*>(ap + i * 4);
#pragma unroll
            for (int i = 0; i < 4; ++i) {
                const float4 u = c[2 * i], v = c[2 * i + 1];
                f16x8 h = {(_Float16)u.x, (_Float16)u.y, (_Float16)u.z, (_Float16)u.w,
                           (_Float16)v.x, (_Float16)v.y, (_Float16)v.z, (_Float16)v.w};
                *reinterpret_cast<f16x8*>(&Ab[am][ak + i * 8]) = h;
            }
        }
        __syncthreads();

#pragma unroll
        for (int kf = 0; kf < 2; ++kf) {
            f16x8 af[4], bf[4];
#pragma unroll
            for (int q = 0; q < 4; ++q)
                af[q] = *reinterpret_cast<const f16x8*>(&Ab[wr * 64 + q * 16 + r][kf * 32 + g * 8]);
#pragma unroll
            for (int q = 0; q < 4; ++q) {
                const int rowb = wc * 64 + q * 16 + r;
                const int e = (g * 16 + kf * 64) ^ ((rowb & 7) << 4);   // bytes
                bf[q] = *reinterpret_cast<const f16x8*>(&Bb[rowb * 64 + (e >> 1)]);
            }
#pragma unroll
            for (int fr = 0; fr < 4; ++fr)
#pragma unroll
                for (int fc = 0; fc < 4; ++fc)
                    acc[fr][fc] = __builtin_amdgcn_mfma_f32_16x16x32_f16(
                        af[fr], bf[fc], acc[fr][fc], 0, 0, 0);
        }
        __syncthreads();
    }

    // ---- epilogue: partial scores over this block's 128 cols
    float ps[4][4];
#pragma unroll
    for (int fr = 0; fr < 4; ++fr)
#pragma unroll
        for (int i = 0; i < 4; ++i) ps[fr][i] = 0.f;

#pragma unroll
    for (int fc = 0; fc < 4; ++fc) {
        const int col = n0 + wc * 64 + fc * 16 + r;
        const float qv = query[(size_t)bat * UNITS + col] + b2[col];
        const float vv = V[col];
#pragma unroll
        for (int fr = 0; fr < 4; ++fr)
#pragma unroll
            for (int i = 0; i < 4; ++i)
                ps[fr][i] += tanh_fast(acc[fr][fc][i] + qv) * vv;
    }
#pragma unroll
    for (int off = 1; off < 16; off <<= 1)
#pragma unroll
        for (int fr = 0; fr < 4; ++fr)
#pragma unroll
            for (int i = 0; i < 4; ++i)
                ps[fr][i] += __shfl_xor(ps[fr][i], off, 64);
    if (r == 0)
#pragma unroll
        for (int fr = 0; fr < 4; ++fr)
#pragma unroll
            for (int i = 0; i < 4; ++i)
                sc_part[wc][wr * 64 + fr * 16 + g * 4 + i] = ps[fr][i];
    __syncthreads();
    if (tid < BM)
        psc[(size_t)n_blk * (BATCH * S_LEN) + row0 + tid] =
            sc_part[0][tid] + sc_part[1][tid];
}

// ---------------- softmax over S per batch (merges the 4 col-block partials;
// bv dropped: softmax is shift-invariant)
__global__ __launch_bounds__(256) void k_softmax(const float* __restrict__ psc,
                                                 float* __restrict__ weights) {
    const int b = blockIdx.x;
    const int tid = threadIdx.x;
    __shared__ float wmax[4], wsum[4];
    float v[8];
    float lm = -1e30f;
#pragma unroll
    for (int i = 0; i < 8; ++i) {
        const size_t idx = (size_t)b * S_LEN + tid + i * 256;
        v[i] = psc[idx] + psc[65536 + idx] + psc[2 * 65536 + idx] + psc[3 * 65536 + idx];
        lm = fmaxf(lm, v[i]);
    }
    for (int off = 32; off; off >>= 1) lm = fmaxf(lm, __shfl_xor(lm, off, 64));
    if ((tid & 63) == 0) wmax[tid >> 6] = lm;
    __syncthreads();
    const float m = fmaxf(fmaxf(wmax[0], wmax[1]), fmaxf(wmax[2], wmax[3]));
    float ls = 0.f;
#pragma unroll
    for (int i = 0; i < 8; ++i) { v[i] = __expf(v[i] - m); ls += v[i]; }
    for (int off = 32; off; off >>= 1) ls += __shfl_xor(ls, off, 64);
    if ((tid & 63) == 0) wsum[tid >> 6] = ls;
    __syncthreads();
    const float inv = 1.f / (wsum[0] + wsum[1] + wsum[2] + wsum[3]);
#pragma unroll
    for (int i = 0; i < 8; ++i)
        weights[(size_t)b * S_LEN + tid + i * 256] = v[i] * inv;
}

// ---------------- context partials
#define SCH 128
#define NCH (S_LEN / SCH)   // 16
__global__ __launch_bounds__(256) void k_ctx_part(const float* __restrict__ enc,
                                                  const float* __restrict__ weights,
                                                  float* __restrict__ part) {
    const int b  = blockIdx.x >> 4;
    const int ch = blockIdx.x & 15;
    const int s0 = ch * SCH;
    const int d4 = threadIdx.x * 4;
    __shared__ float wl[SCH];
    if (threadIdx.x < SCH) wl[threadIdx.x] = weights[(size_t)b * S_LEN + s0 + threadIdx.x];
    __syncthreads();
    float4 a = {0.f, 0.f, 0.f, 0.f};
    const float* base = enc + (size_t)b * S_LEN * D_ENC + (size_t)s0 * D_ENC + d4;
#pragma unroll 4
    for (int s = 0; s < SCH; ++s) {
        const float4 e = *reinterpret_cast<const float4*>(base + (size_t)s * D_ENC);
        const float w = wl[s];
        a.x += w * e.x; a.y += w * e.y; a.z += w * e.z; a.w += w * e.w;
    }
    *reinterpret_cast<float4*>(&part[(size_t)blockIdx.x * D_ENC + d4]) = a;
}

__global__ __launch_bounds__(256) void k_ctx_combine(const float* __restrict__ part,
                                                     float* __restrict__ ctx) {
    const int idx = blockIdx.x * 256 + threadIdx.x;  // 0..32767
    const int b = idx >> 10;
    const int d = idx & 1023;
    float s = 0.f;
#pragma unroll
    for (int c = 0; c < NCH; ++c) s += part[(size_t)(b * NCH + c) * D_ENC + d];
    ctx[idx] = s;
}

extern "C" void kernel_launch(void* const* d_in, const int* in_sizes, int n_in,
                              void* d_out, int out_size, void* d_ws, size_t ws_size,
                              hipStream_t stream) {
    const float* dec = (const float*)d_in[0];   // [32,1,1024]
    const float* enc = (const float*)d_in[1];   // [32,2048,1024]
    const float* W1  = (const float*)d_in[2];   // [1024,512]
    const float* b1  = (const float*)d_in[3];   // [512]
    const float* W2  = (const float*)d_in[4];   // [1024,512]
    const float* b2  = (const float*)d_in[5];   // [512]
    const float* V   = (const float*)d_in[6];   // [512,1]
    // bv = d_in[7] unused: softmax is shift-invariant

    float* out = (float*)d_out;
    float* out_ctx = out;                 // [32,1024]
    float* out_w   = out + BATCH * D_ENC; // [32,2048]

    char* ws = (char*)d_ws;
    _Float16* W2h = (_Float16*)(ws);                        // 1 MB
    float* query  = (float*)(ws + (1 << 20));               // 64 KB
    float* psc    = (float*)(ws + (1 << 20) + (1 << 16));   // 4 x 65536 f32 = 1 MB
    float* part   = (float*)(ws + (2 << 20) + (1 << 16) + (1 << 18)); // 2 MB

    k_prep_w2<<<dim3(D_DEC / 32, UNITS / 32), dim3(32, 8), 0, stream>>>(W2, W2h);
    k_query<<<BATCH, 512, 0, stream>>>(dec, W1, b1, query);
    k_scores<<<2048, 256, 0, stream>>>(enc, W2h, query, b2, V, psc);
    k_softmax<<<BATCH, 256, 0, stream>>>(psc, out_w);
    k_ctx_part<<<BATCH * NCH, 256, 0, stream>>>(enc, out_w, part);
    k_ctx_combine<<<(BATCH * D_ENC) / 256, 256, 0, stream>>>(part, out_ctx);
}

// Round 3
// 233.889 us; speedup vs baseline: 1.4569x; 1.0489x over previous
//
#include <hip/hip_runtime.h>
#include <hip/hip_bf16.h>
#include <hip/hip_fp16.h>

#define UNITS 512
#define D_DEC 1024
#define D_ENC 1024
#define BATCH 32
#define S_LEN 2048

typedef _Float16 f16x8 __attribute__((ext_vector_type(8)));
typedef float f32x4 __attribute__((ext_vector_type(4)));

__device__ inline float tanh_fast(float x) {
    float e = __expf(2.f * x);
    return 1.f - 2.f * __builtin_amdgcn_rcpf(e + 1.f);
}

// ---------------- prep: transpose + convert W2 [1024][512] f32 -> W2h [512][1024] f16
__global__ __launch_bounds__(256) void k_prep_w2(const float* __restrict__ W2,
                                                 _Float16* __restrict__ W2h) {
    __shared__ float tile[32][33];
    const int kb = blockIdx.x * 32;
    const int nb = blockIdx.y * 32;
    const int tx = threadIdx.x;
    const int ty = threadIdx.y;
    for (int i = 0; i < 32; i += 8)
        tile[ty + i][tx] = W2[(size_t)(kb + ty + i) * UNITS + nb + tx];
    __syncthreads();
    for (int i = 0; i < 32; i += 8)
        W2h[(size_t)(nb + ty + i) * D_DEC + kb + tx] = (_Float16)tile[tx][ty + i];
}

// ---------------- query: 16 blocks x 1024 thr; block covers u-slice of 32 for all batches
__global__ __launch_bounds__(1024) void k_query(const float* __restrict__ dec,
                                                const float* __restrict__ W1,
                                                const float* __restrict__ b1,
                                                float* __restrict__ query) {
    const int u = blockIdx.x * 32 + (threadIdx.x & 31);
    const int b = threadIdx.x >> 5;
    float acc = b1[u];
    const float* dp = dec + (size_t)b * D_DEC;
    for (int d = 0; d < D_DEC; ++d) acc += dp[d] * W1[(size_t)d * UNITS + u];
    query[(size_t)b * UNITS + u] = acc;
}

// ---------------- scores: M=65536 K=1024 N=512 f16 MFMA GEMM, fused tanh*V reduce.
// Per block: 128 rows x 512 cols, 8 waves (2 row-halves x 4 col-quarters), wave tile 64x128.
// BK=32, double-buffered LDS, 2-phase pipeline (stage t+1 before compute t).
#define BM 128
#define BKK 32
#define NSTEP (D_DEC / BKK)

__global__ __launch_bounds__(512, 2) void k_scores(const float* __restrict__ enc,
                                                   const _Float16* __restrict__ W2h,
                                                   const float* __restrict__ query,
                                                   const float* __restrict__ b2,
                                                   const float* __restrict__ V,
                                                   float* __restrict__ scores) {
    __shared__ __align__(16) _Float16 Ab[2][BM * BKK];      // 2 x 8 KB
    __shared__ __align__(16) _Float16 Bb[2][UNITS * BKK];   // 2 x 32 KB
    __shared__ float sc_part[4][BM];                        // 2 KB

    const int tid  = threadIdx.x;
    const int lane = tid & 63;
    const int w    = tid >> 6;     // 0..7
    const int wr   = w >> 2;       // 0..1: rows [wr*64, wr*64+64)
    const int wc   = w & 3;        // 0..3: cols [wc*128, wc*128+128)
    const int g    = lane >> 4;    // 0..3
    const int r    = lane & 15;    // 0..15
    const int row0 = blockIdx.x * BM;
    const int bat  = row0 >> 11;

    // A staging: thread -> row tid>>2, 8 fp32 at k-local (tid&3)*8; swizzled LDS write
    const int arow   = tid >> 2;
    const int acl    = (tid & 3);
    const float* aptr = enc + (size_t)(row0 + arow) * D_ENC + acl * 8;
    const int a_wbyte = arow * 64 + ((acl * 16) ^ (((arow >> 1) & 3) << 4));

    f32x4 acc[4][8];
#pragma unroll
    for (int i = 0; i < 4; ++i)
#pragma unroll
        for (int j = 0; j < 8; ++j) acc[i][j] = (f32x4){0.f, 0.f, 0.f, 0.f};

    // ---- prologue: stage tile 0
    {
        const float4 p0 = *reinterpret_cast<const float4*>(aptr);
        const float4 p1 = *reinterpret_cast<const float4*>(aptr + 4);
#pragma unroll
        for (int i = 0; i < 4; ++i) {
            const int g16 = i * 512 + tid;
            const int n   = g16 >> 2;
            const int j   = g16 & 3;
            const int kel = ((j * 16) ^ (((n >> 1) & 3) << 4)) >> 1;
            const _Float16* src = W2h + (size_t)n * D_DEC + kel;
            _Float16* dst = &Bb[0][g16 * 8];
            __builtin_amdgcn_global_load_lds(
                (const __attribute__((address_space(1))) void*)src,
                (__attribute__((address_space(3))) void*)dst, 16, 0, 0);
        }
        f16x8 h = {(_Float16)p0.x, (_Float16)p0.y, (_Float16)p0.z, (_Float16)p0.w,
                   (_Float16)p1.x, (_Float16)p1.y, (_Float16)p1.z, (_Float16)p1.w};
        *reinterpret_cast<f16x8*>((char*)&Ab[0][0] + a_wbyte) = h;
    }
    __syncthreads();

    // ---- main loop: one barrier per step
    for (int t = 0; t < NSTEP; ++t) {
        const int cur = t & 1;
        float4 p0, p1;
        if (t + 1 < NSTEP) {
            const int k0 = (t + 1) * BKK;
            p0 = *reinterpret_cast<const float4*>(aptr + k0);
            p1 = *reinterpret_cast<const float4*>(aptr + k0 + 4);
#pragma unroll
            for (int i = 0; i < 4; ++i) {
                const int g16 = i * 512 + tid;
                const int n   = g16 >> 2;
                const int j   = g16 & 3;
                const int kel = ((j * 16) ^ (((n >> 1) & 3) << 4)) >> 1;
                const _Float16* src = W2h + (size_t)n * D_DEC + k0 + kel;
                _Float16* dst = &Bb[cur ^ 1][g16 * 8];
                __builtin_amdgcn_global_load_lds(
                    (const __attribute__((address_space(1))) void*)src,
                    (__attribute__((address_space(3))) void*)dst, 16, 0, 0);
            }
        }

        f16x8 af[4], bf[8];
#pragma unroll
        for (int q = 0; q < 4; ++q) {
            const int rowa = wr * 64 + q * 16 + r;
            const int off  = rowa * 64 + ((g * 16) ^ (((rowa >> 1) & 3) << 4));
            af[q] = *reinterpret_cast<const f16x8*>((const char*)&Ab[cur][0] + off);
        }
#pragma unroll
        for (int q = 0; q < 8; ++q) {
            const int rowb = wc * 128 + q * 16 + r;
            const int off  = rowb * 64 + ((g * 16) ^ (((rowb >> 1) & 3) << 4));
            bf[q] = *reinterpret_cast<const f16x8*>((const char*)&Bb[cur][0] + off);
        }
#pragma unroll
        for (int fr = 0; fr < 4; ++fr)
#pragma unroll
            for (int fc = 0; fc < 8; ++fc)
                acc[fr][fc] = __builtin_amdgcn_mfma_f32_16x16x32_f16(
                    af[fr], bf[fc], acc[fr][fc], 0, 0, 0);

        if (t + 1 < NSTEP) {
            f16x8 h = {(_Float16)p0.x, (_Float16)p0.y, (_Float16)p0.z, (_Float16)p0.w,
                       (_Float16)p1.x, (_Float16)p1.y, (_Float16)p1.z, (_Float16)p1.w};
            *reinterpret_cast<f16x8*>((char*)&Ab[cur ^ 1][0] + a_wbyte) = h;
        }
        __syncthreads();
    }

    // ---- epilogue: scores = sum over cols of tanh(val + query + b2) * V
    float qv[8], vv[8];
#pragma unroll
    for (int fc = 0; fc < 8; ++fc) {
        const int col = wc * 128 + fc * 16 + r;
        qv[fc] = query[(size_t)bat * UNITS + col] + b2[col];
        vv[fc] = V[col];
    }
    float ps[4][4];
#pragma unroll
    for (int fr = 0; fr < 4; ++fr)
#pragma unroll
        for (int i = 0; i < 4; ++i) ps[fr][i] = 0.f;
#pragma unroll
    for (int fc = 0; fc < 8; ++fc)
#pragma unroll
        for (int fr = 0; fr < 4; ++fr)
#pragma unroll
            for (int i = 0; i < 4; ++i)
                ps[fr][i] += tanh_fast(acc[fr][fc][i] + qv[fc]) * vv[fc];
#pragma unroll
    for (int off = 1; off < 16; off <<= 1)
#pragma unroll
        for (int fr = 0; fr < 4; ++fr)
#pragma unroll
            for (int i = 0; i < 4; ++i)
                ps[fr][i] += __shfl_xor(ps[fr][i], off, 64);
    if (r == 0)
#pragma unroll
        for (int fr = 0; fr < 4; ++fr)
#pragma unroll
            for (int i = 0; i < 4; ++i)
                sc_part[wc][wr * 64 + fr * 16 + g * 4 + i] = ps[fr][i];
    __syncthreads();
    if (tid < BM)
        scores[(size_t)row0 + tid] =
            sc_part[0][tid] + sc_part[1][tid] + sc_part[2][tid] + sc_part[3][tid];
}

// ---------------- softmax over S per batch (bv dropped: shift-invariant)
__global__ __launch_bounds__(256) void k_softmax(const float* __restrict__ scores,
                                                 float* __restrict__ weights) {
    const int b = blockIdx.x;
    const int tid = threadIdx.x;
    const float* s = scores + (size_t)b * S_LEN;
    __shared__ float wmax[4], wsum[4];
    float v[8];
    float lm = -1e30f;
#pragma unroll
    for (int i = 0; i < 8; ++i) { v[i] = s[tid + i * 256]; lm = fmaxf(lm, v[i]); }
    for (int off = 32; off; off >>= 1) lm = fmaxf(lm, __shfl_xor(lm, off, 64));
    if ((tid & 63) == 0) wmax[tid >> 6] = lm;
    __syncthreads();
    const float m = fmaxf(fmaxf(wmax[0], wmax[1]), fmaxf(wmax[2], wmax[3]));
    float ls = 0.f;
#pragma unroll
    for (int i = 0; i < 8; ++i) { v[i] = __expf(v[i] - m); ls += v[i]; }
    for (int off = 32; off; off >>= 1) ls += __shfl_xor(ls, off, 64);
    if ((tid & 63) == 0) wsum[tid >> 6] = ls;
    __syncthreads();
    const float inv = 1.f / (wsum[0] + wsum[1] + wsum[2] + wsum[3]);
#pragma unroll
    for (int i = 0; i < 8; ++i)
        weights[(size_t)b * S_LEN + tid + i * 256] = v[i] * inv;
}

// ---------------- context partials
#define SCH 128
#define NCH (S_LEN / SCH)
__global__ __launch_bounds__(256) void k_ctx_part(const float* __restrict__ enc,
                                                  const float* __restrict__ weights,
                                                  float* __restrict__ part) {
    const int b  = blockIdx.x >> 4;
    const int ch = blockIdx.x & 15;
    const int s0 = ch * SCH;
    const int d4 = threadIdx.x * 4;
    __shared__ float wl[SCH];
    if (threadIdx.x < SCH) wl[threadIdx.x] = weights[(size_t)b * S_LEN + s0 + threadIdx.x];
    __syncthreads();
    float4 a = {0.f, 0.f, 0.f, 0.f};
    const float* base = enc + (size_t)b * S_LEN * D_ENC + (size_t)s0 * D_ENC + d4;
#pragma unroll 4
    for (int s = 0; s < SCH; ++s) {
        const float4 e = *reinterpret_cast<const float4*>(base + (size_t)s * D_ENC);
        const float w = wl[s];
        a.x += w * e.x; a.y += w * e.y; a.z += w * e.z; a.w += w * e.w;
    }
    *reinterpret_cast<float4*>(&part[(size_t)blockIdx.x * D_ENC + d4]) = a;
}

__global__ __launch_bounds__(256) void k_ctx_combine(const float* __restrict__ part,
                                                     float* __restrict__ ctx) {
    const int idx = blockIdx.x * 256 + threadIdx.x;
    const int b = idx >> 10;
    const int d = idx & 1023;
    float s = 0.f;
#pragma unroll
    for (int c = 0; c < NCH; ++c) s += part[(size_t)(b * NCH + c) * D_ENC + d];
    ctx[idx] = s;
}

extern "C" void kernel_launch(void* const* d_in, const int* in_sizes, int n_in,
                              void* d_out, int out_size, void* d_ws, size_t ws_size,
                              hipStream_t stream) {
    const float* dec = (const float*)d_in[0];
    const float* enc = (const float*)d_in[1];
    const float* W1  = (const float*)d_in[2];
    const float* b1  = (const float*)d_in[3];
    const float* W2  = (const float*)d_in[4];
    const float* b2  = (const float*)d_in[5];
    const float* V   = (const float*)d_in[6];
    // bv unused: softmax shift-invariant

    float* out = (float*)d_out;
    float* out_ctx = out;                 // [32,1024]
    float* out_w   = out + BATCH * D_ENC; // [32,2048]

    char* ws = (char*)d_ws;
    _Float16* W2h = (_Float16*)(ws);                        // 1 MB
    float* query  = (float*)(ws + (1 << 20));               // 64 KB
    float* scores = (float*)(ws + (1 << 20) + (1 << 16));   // 256 KB
    float* part   = (float*)(ws + (1 << 20) + (1 << 16) + (1 << 18)); // 2 MB

    k_prep_w2<<<dim3(D_DEC / 32, UNITS / 32), dim3(32, 8), 0, stream>>>(W2, W2h);
    k_query<<<UNITS / 32, 1024, 0, stream>>>(dec, W1, b1, query);
    k_scores<<<(BATCH * S_LEN) / BM, 512, 0, stream>>>(enc, W2h, query, b2, V, scores);
    k_softmax<<<BATCH, 256, 0, stream>>>(scores, out_w);
    k_ctx_part<<<BATCH * NCH, 256, 0, stream>>>(enc, out_w, part);
    k_ctx_combine<<<(BATCH * D_ENC) / 256, 256, 0, stream>>>(part, out_ctx);
}

// Round 4
// 217.442 us; speedup vs baseline: 1.5671x; 1.0756x over previous
//
#include <hip/hip_runtime.h>
#include <hip/hip_bf16.h>
#include <hip/hip_fp16.h>

#define UNITS 512
#define D_DEC 1024
#define D_ENC 1024
#define BATCH 32
#define S_LEN 2048

typedef _Float16 f16x8 __attribute__((ext_vector_type(8)));
typedef float f32x4 __attribute__((ext_vector_type(4)));

__device__ inline float tanh_fast(float x) {
    float e = __expf(2.f * x);
    return 1.f - 2.f * __builtin_amdgcn_rcpf(e + 1.f);
}

// ---------------- prep: transpose + convert W2 [1024][512] f32 -> W2h [512][1024] f16
__global__ __launch_bounds__(256) void k_prep_w2(const float* __restrict__ W2,
                                                 _Float16* __restrict__ W2h) {
    __shared__ float tile[32][33];
    const int kb = blockIdx.x * 32;
    const int nb = blockIdx.y * 32;
    const int tx = threadIdx.x;
    const int ty = threadIdx.y;
    for (int i = 0; i < 32; i += 8)
        tile[ty + i][tx] = W2[(size_t)(kb + ty + i) * UNITS + nb + tx];
    __syncthreads();
    for (int i = 0; i < 32; i += 8)
        W2h[(size_t)(nb + ty + i) * D_DEC + kb + tx] = (_Float16)tile[tx][ty + i];
}

// ---------------- query
__global__ __launch_bounds__(1024) void k_query(const float* __restrict__ dec,
                                                const float* __restrict__ W1,
                                                const float* __restrict__ b1,
                                                float* __restrict__ query) {
    const int u = blockIdx.x * 32 + (threadIdx.x & 31);
    const int b = threadIdx.x >> 5;
    float acc = b1[u];
    const float* dp = dec + (size_t)b * D_DEC;
    for (int d = 0; d < D_DEC; ++d) acc += dp[d] * W1[(size_t)d * UNITS + u];
    query[(size_t)b * UNITS + u] = acc;
}

// ---------------- scores: M=65536 K=1024 N=512 f16 MFMA GEMM, fused tanh*V reduce.
// 2-way n-split: block = 128 rows x 256 cols, 8 waves of 64x64, BK=32, LDS dbuf,
// 2-phase pipeline. Partial scores psc[2][65536]; softmax merges.
#define BM 128
#define BN 256
#define BKK 32
#define NSTEP (D_DEC / BKK)

__global__ __launch_bounds__(512, 4) void k_scores(const float* __restrict__ enc,
                                                   const _Float16* __restrict__ W2h,
                                                   const float* __restrict__ query,
                                                   const float* __restrict__ b2,
                                                   const float* __restrict__ V,
                                                   float* __restrict__ psc) {
    __shared__ __align__(16) _Float16 Ab[2][BM * BKK];   // 2 x 8 KB
    __shared__ __align__(16) _Float16 Bb[2][BN * BKK];   // 2 x 16 KB
    __shared__ float sc_part[4][BM];                     // 2 KB

    const int tid  = threadIdx.x;
    const int lane = tid & 63;
    const int w    = tid >> 6;     // 0..7
    const int wr   = w >> 2;       // 0..1: rows [wr*64, +64)
    const int wc   = w & 3;        // 0..3: cols [wc*64, +64)
    const int g    = lane >> 4;    // 0..3
    const int r    = lane & 15;    // 0..15

    // XCD pairing: wg and wg+8 have equal %8 residue -> same XCD; map them to
    // the (n=0, n=1) pair of one m-tile.  mapped = (wg&7)*128 + (wg>>3), bijective.
    const unsigned wg = blockIdx.x;
    const int mapped = (int)((wg & 7) * 128 + (wg >> 3));
    const int m_blk  = mapped >> 1;
    const int n_blk  = mapped & 1;
    const int row0   = m_blk * BM;
    const int n0     = n_blk * BN;
    const int bat    = row0 >> 11;

    // A staging: thread -> row tid>>2, 8 fp32 at (tid&3)*8; swizzled LDS write
    const int arow = tid >> 2;
    const int acl  = tid & 3;
    const float* aptr = enc + (size_t)(row0 + arow) * D_ENC + acl * 8;
    const int a_wbyte = arow * 64 + ((acl * 16) ^ (((arow >> 1) & 3) << 4));

    f32x4 acc[4][4];
#pragma unroll
    for (int i = 0; i < 4; ++i)
#pragma unroll
        for (int j = 0; j < 4; ++j) acc[i][j] = (f32x4){0.f, 0.f, 0.f, 0.f};

    // ---- prologue: stage tile 0
    {
        const float4 p0 = *reinterpret_cast<const float4*>(aptr);
        const float4 p1 = *reinterpret_cast<const float4*>(aptr + 4);
#pragma unroll
        for (int i = 0; i < 2; ++i) {
            const int g16 = i * 512 + tid;           // 0..1023: 16B granules
            const int n   = g16 >> 2;                // 0..255
            const int j   = g16 & 3;
            const int kel = ((j * 16) ^ (((n >> 1) & 3) << 4)) >> 1;
            const _Float16* src = W2h + (size_t)(n0 + n) * D_DEC + kel;
            _Float16* dst = &Bb[0][g16 * 8];
            __builtin_amdgcn_global_load_lds(
                (const __attribute__((address_space(1))) void*)src,
                (__attribute__((address_space(3))) void*)dst, 16, 0, 0);
        }
        f16x8 h = {(_Float16)p0.x, (_Float16)p0.y, (_Float16)p0.z, (_Float16)p0.w,
                   (_Float16)p1.x, (_Float16)p1.y, (_Float16)p1.z, (_Float16)p1.w};
        *reinterpret_cast<f16x8*>((char*)&Ab[0][0] + a_wbyte) = h;
    }
    __syncthreads();

    // ---- main loop: one barrier per step
    for (int t = 0; t < NSTEP; ++t) {
        const int cur = t & 1;
        float4 p0, p1;
        if (t + 1 < NSTEP) {
            const int k0 = (t + 1) * BKK;
            p0 = *reinterpret_cast<const float4*>(aptr + k0);
            p1 = *reinterpret_cast<const float4*>(aptr + k0 + 4);
#pragma unroll
            for (int i = 0; i < 2; ++i) {
                const int g16 = i * 512 + tid;
                const int n   = g16 >> 2;
                const int j   = g16 & 3;
                const int kel = ((j * 16) ^ (((n >> 1) & 3) << 4)) >> 1;
                const _Float16* src = W2h + (size_t)(n0 + n) * D_DEC + k0 + kel;
                _Float16* dst = &Bb[cur ^ 1][g16 * 8];
                __builtin_amdgcn_global_load_lds(
                    (const __attribute__((address_space(1))) void*)src,
                    (__attribute__((address_space(3))) void*)dst, 16, 0, 0);
            }
        }

        f16x8 af[4], bf[4];
#pragma unroll
        for (int q = 0; q < 4; ++q) {
            const int rowa = wr * 64 + q * 16 + r;
            const int off  = rowa * 64 + ((g * 16) ^ (((rowa >> 1) & 3) << 4));
            af[q] = *reinterpret_cast<const f16x8*>((const char*)&Ab[cur][0] + off);
        }
#pragma unroll
        for (int q = 0; q < 4; ++q) {
            const int rowb = wc * 64 + q * 16 + r;
            const int off  = rowb * 64 + ((g * 16) ^ (((rowb >> 1) & 3) << 4));
            bf[q] = *reinterpret_cast<const f16x8*>((const char*)&Bb[cur][0] + off);
        }
#pragma unroll
        for (int fr = 0; fr < 4; ++fr)
#pragma unroll
            for (int fc = 0; fc < 4; ++fc)
                acc[fr][fc] = __builtin_amdgcn_mfma_f32_16x16x32_f16(
                    af[fr], bf[fc], acc[fr][fc], 0, 0, 0);

        if (t + 1 < NSTEP) {
            f16x8 h = {(_Float16)p0.x, (_Float16)p0.y, (_Float16)p0.z, (_Float16)p0.w,
                       (_Float16)p1.x, (_Float16)p1.y, (_Float16)p1.z, (_Float16)p1.w};
            *reinterpret_cast<f16x8*>((char*)&Ab[cur ^ 1][0] + a_wbyte) = h;
        }
        __syncthreads();
    }

    // ---- epilogue: partial over this block's 256 cols
    float qv[4], vv[4];
#pragma unroll
    for (int fc = 0; fc < 4; ++fc) {
        const int col = n0 + wc * 64 + fc * 16 + r;
        qv[fc] = query[(size_t)bat * UNITS + col] + b2[col];
        vv[fc] = V[col];
    }
    float ps[4][4];
#pragma unroll
    for (int fr = 0; fr < 4; ++fr)
#pragma unroll
        for (int i = 0; i < 4; ++i) ps[fr][i] = 0.f;
#pragma unroll
    for (int fc = 0; fc < 4; ++fc)
#pragma unroll
        for (int fr = 0; fr < 4; ++fr)
#pragma unroll
            for (int i = 0; i < 4; ++i)
                ps[fr][i] += tanh_fast(acc[fr][fc][i] + qv[fc]) * vv[fc];
#pragma unroll
    for (int off = 1; off < 16; off <<= 1)
#pragma unroll
        for (int fr = 0; fr < 4; ++fr)
#pragma unroll
            for (int i = 0; i < 4; ++i)
                ps[fr][i] += __shfl_xor(ps[fr][i], off, 64);
    if (r == 0)
#pragma unroll
        for (int fr = 0; fr < 4; ++fr)
#pragma unroll
            for (int i = 0; i < 4; ++i)
                sc_part[wc][wr * 64 + fr * 16 + g * 4 + i] = ps[fr][i];
    __syncthreads();
    if (tid < BM)
        psc[(size_t)n_blk * 65536 + row0 + tid] =
            sc_part[0][tid] + sc_part[1][tid] + sc_part[2][tid] + sc_part[3][tid];
}

// ---------------- softmax (merges 2 n-planes; bv dropped: shift-invariant)
__global__ __launch_bounds__(256) void k_softmax(const float* __restrict__ psc,
                                                 float* __restrict__ weights) {
    const int b = blockIdx.x;
    const int tid = threadIdx.x;
    __shared__ float wmax[4], wsum[4];
    float v[8];
    float lm = -1e30f;
#pragma unroll
    for (int i = 0; i < 8; ++i) {
        const size_t idx = (size_t)b * S_LEN + tid + i * 256;
        v[i] = psc[idx] + psc[65536 + idx];
        lm = fmaxf(lm, v[i]);
    }
    for (int off = 32; off; off >>= 1) lm = fmaxf(lm, __shfl_xor(lm, off, 64));
    if ((tid & 63) == 0) wmax[tid >> 6] = lm;
    __syncthreads();
    const float m = fmaxf(fmaxf(wmax[0], wmax[1]), fmaxf(wmax[2], wmax[3]));
    float ls = 0.f;
#pragma unroll
    for (int i = 0; i < 8; ++i) { v[i] = __expf(v[i] - m); ls += v[i]; }
    for (int off = 32; off; off >>= 1) ls += __shfl_xor(ls, off, 64);
    if ((tid & 63) == 0) wsum[tid >> 6] = ls;
    __syncthreads();
    const float inv = 1.f / (wsum[0] + wsum[1] + wsum[2] + wsum[3]);
#pragma unroll
    for (int i = 0; i < 8; ++i)
        weights[(size_t)b * S_LEN + tid + i * 256] = v[i] * inv;
}

// ---------------- context partials
#define SCH 128
#define NCH (S_LEN / SCH)
__global__ __launch_bounds__(256) void k_ctx_part(const float* __restrict__ enc,
                                                  const float* __restrict__ weights,
                                                  float* __restrict__ part) {
    const int b  = blockIdx.x >> 4;
    const int ch = blockIdx.x & 15;
    const int s0 = ch * SCH;
    const int d4 = threadIdx.x * 4;
    __shared__ float wl[SCH];
    if (threadIdx.x < SCH) wl[threadIdx.x] = weights[(size_t)b * S_LEN + s0 + threadIdx.x];
    __syncthreads();
    float4 a = {0.f, 0.f, 0.f, 0.f};
    const float* base = enc + (size_t)b * S_LEN * D_ENC + (size_t)s0 * D_ENC + d4;
#pragma unroll 4
    for (int s = 0; s < SCH; ++s) {
        const float4 e = *reinterpret_cast<const float4*>(base + (size_t)s * D_ENC);
        const float w = wl[s];
        a.x += w * e.x; a.y += w * e.y; a.z += w * e.z; a.w += w * e.w;
    }
    *reinterpret_cast<float4*>(&part[(size_t)blockIdx.x * D_ENC + d4]) = a;
}

__global__ __launch_bounds__(256) void k_ctx_combine(const float* __restrict__ part,
                                                     float* __restrict__ ctx) {
    const int idx = blockIdx.x * 256 + threadIdx.x;
    const int b = idx >> 10;
    const int d = idx & 1023;
    float s = 0.f;
#pragma unroll
    for (int c = 0; c < NCH; ++c) s += part[(size_t)(b * NCH + c) * D_ENC + d];
    ctx[idx] = s;
}

extern "C" void kernel_launch(void* const* d_in, const int* in_sizes, int n_in,
                              void* d_out, int out_size, void* d_ws, size_t ws_size,
                              hipStream_t stream) {
    const float* dec = (const float*)d_in[0];
    const float* enc = (const float*)d_in[1];
    const float* W1  = (const float*)d_in[2];
    const float* b1  = (const float*)d_in[3];
    const float* W2  = (const float*)d_in[4];
    const float* b2  = (const float*)d_in[5];
    const float* V   = (const float*)d_in[6];
    // bv unused: softmax shift-invariant

    float* out = (float*)d_out;
    float* out_ctx = out;
    float* out_w   = out + BATCH * D_ENC;

    char* ws = (char*)d_ws;
    _Float16* W2h = (_Float16*)(ws);                        // 1 MB
    float* query  = (float*)(ws + (1 << 20));               // 64 KB
    float* psc    = (float*)(ws + (1 << 20) + (1 << 16));   // 512 KB (2 planes)
    float* part   = (float*)(ws + (1 << 20) + (1 << 16) + (1 << 19)); // 2 MB

    k_prep_w2<<<dim3(D_DEC / 32, UNITS / 32), dim3(32, 8), 0, stream>>>(W2, W2h);
    k_query<<<UNITS / 32, 1024, 0, stream>>>(dec, W1, b1, query);
    k_scores<<<(BATCH * S_LEN) / BM * 2, 512, 0, stream>>>(enc, W2h, query, b2, V, psc);
    k_softmax<<<BATCH, 256, 0, stream>>>(psc, out_w);
    k_ctx_part<<<BATCH * NCH, 256, 0, stream>>>(enc, out_w, part);
    k_ctx_combine<<<(BATCH * D_ENC) / 256, 256, 0, stream>>>(part, out_ctx);
}

// Round 5
// 216.864 us; speedup vs baseline: 1.5713x; 1.0027x over previous
//
#include <hip/hip_runtime.h>
#include <hip/hip_bf16.h>
#include <hip/hip_fp16.h>

#define UNITS 512
#define D_DEC 1024
#define D_ENC 1024
#define BATCH 32
#define S_LEN 2048

typedef _Float16 f16x8 __attribute__((ext_vector_type(8)));
typedef float f32x4 __attribute__((ext_vector_type(4)));

__device__ inline float tanh_fast(float x) {
    float e = __expf(2.f * x);
    return 1.f - 2.f * __builtin_amdgcn_rcpf(e + 1.f);
}

// ---------------- prep: transpose + convert W2 [1024][512] f32 -> W2h [512][1024] f16
__global__ __launch_bounds__(256) void k_prep_w2(const float* __restrict__ W2,
                                                 _Float16* __restrict__ W2h) {
    __shared__ float tile[32][33];
    const int kb = blockIdx.x * 32;
    const int nb = blockIdx.y * 32;
    const int tx = threadIdx.x;
    const int ty = threadIdx.y;
    for (int i = 0; i < 32; i += 8)
        tile[ty + i][tx] = W2[(size_t)(kb + ty + i) * UNITS + nb + tx];
    __syncthreads();
    for (int i = 0; i < 32; i += 8)
        W2h[(size_t)(nb + ty + i) * D_DEC + kb + tx] = (_Float16)tile[tx][ty + i];
}

// ---------------- query
__global__ __launch_bounds__(1024) void k_query(const float* __restrict__ dec,
                                                const float* __restrict__ W1,
                                                const float* __restrict__ b1,
                                                float* __restrict__ query) {
    const int u = blockIdx.x * 32 + (threadIdx.x & 31);
    const int b = threadIdx.x >> 5;
    float acc = b1[u];
    const float* dp = dec + (size_t)b * D_DEC;
    for (int d = 0; d < D_DEC; ++d) acc += dp[d] * W1[(size_t)d * UNITS + u];
    query[(size_t)b * UNITS + u] = acc;
}

// ---------------- scores: M=65536 K=1024 N=512 f16 MFMA GEMM, fused tanh*V reduce.
// Block = 128 rows x 256 cols (2-way n-split), 8 waves of 64x64, BK=32.
// Counted-vmcnt pipeline: B triple-buffered via global_load_lds (prefetch dist 2),
// A reg-prefetch dist 2; barriers are lgkmcnt(0)+s_barrier (NO vmcnt drain) so
// 4 loads stay in flight across every barrier (T3+T4).
#define BM 128
#define BN 256
#define BKK 32
#define NSTEP (D_DEC / BKK)

#define SOFT_BAR() do { \
    asm volatile("s_waitcnt lgkmcnt(0)" ::: "memory"); \
    __builtin_amdgcn_s_barrier(); \
    asm volatile("" ::: "memory"); \
} while (0)

__global__ __launch_bounds__(512, 4) void k_scores(const float* __restrict__ enc,
                                                   const _Float16* __restrict__ W2h,
                                                   const float* __restrict__ query,
                                                   const float* __restrict__ b2,
                                                   const float* __restrict__ V,
                                                   float* __restrict__ psc) {
    __shared__ __align__(16) _Float16 Ab[2][BM * BKK];   // 2 x 8 KB
    __shared__ __align__(16) _Float16 Bb[3][BN * BKK];   // 3 x 16 KB
    __shared__ float sc_part[4][BM];                     // 2 KB

    const int tid  = threadIdx.x;
    const int lane = tid & 63;
    const int w    = tid >> 6;
    const int wr   = w >> 2;       // 0..1
    const int wc   = w & 3;        // 0..3
    const int g    = lane >> 4;
    const int r    = lane & 15;

    // XCD pairing: wg and wg+8 share %8 residue -> same XCD; map to (n0,n1) of one m-tile.
    const unsigned wg = blockIdx.x;
    const int mapped = (int)((wg & 7) * 128 + (wg >> 3));
    const int m_blk  = mapped >> 1;
    const int n_blk  = mapped & 1;
    const int row0   = m_blk * BM;
    const int n0     = n_blk * BN;
    const int bat    = row0 >> 11;

    const int arow = tid >> 2;
    const int acl  = tid & 3;
    const float* aptr = enc + (size_t)(row0 + arow) * D_ENC + acl * 8;
    const int a_wbyte = arow * 64 + ((acl * 16) ^ (((arow >> 1) & 3) << 4));

    f32x4 acc[4][4];
#pragma unroll
    for (int i = 0; i < 4; ++i)
#pragma unroll
        for (int j = 0; j < 4; ++j) acc[i][j] = (f32x4){0.f, 0.f, 0.f, 0.f};

    auto gldb = [&](int tile, int buf) {
#pragma unroll
        for (int i = 0; i < 2; ++i) {
            const int g16 = i * 512 + tid;
            const int n   = g16 >> 2;
            const int j   = g16 & 3;
            const int kel = ((j * 16) ^ (((n >> 1) & 3) << 4)) >> 1;
            const _Float16* src = W2h + (size_t)(n0 + n) * D_DEC + tile * BKK + kel;
            __builtin_amdgcn_global_load_lds(
                (const __attribute__((address_space(1))) void*)src,
                (__attribute__((address_space(3))) void*)&Bb[buf][g16 * 8], 16, 0, 0);
        }
    };
    auto lda = [&](int tile, float4& a, float4& b) {
        a = *reinterpret_cast<const float4*>(aptr + tile * BKK);
        b = *reinterpret_cast<const float4*>(aptr + tile * BKK + 4);
    };
    auto sta = [&](const float4& a, const float4& b, int buf) {
        f16x8 h = {(_Float16)a.x, (_Float16)a.y, (_Float16)a.z, (_Float16)a.w,
                   (_Float16)b.x, (_Float16)b.y, (_Float16)b.z, (_Float16)b.w};
        *reinterpret_cast<f16x8*>((char*)&Ab[buf][0] + a_wbyte) = h;
    };
    auto comp = [&](int abuf, int bbuf) {
        f16x8 af[4], bf[4];
#pragma unroll
        for (int q = 0; q < 4; ++q) {
            const int rowa = wr * 64 + q * 16 + r;
            const int off  = rowa * 64 + ((g * 16) ^ (((rowa >> 1) & 3) << 4));
            af[q] = *reinterpret_cast<const f16x8*>((const char*)&Ab[abuf][0] + off);
        }
#pragma unroll
        for (int q = 0; q < 4; ++q) {
            const int rowb = wc * 64 + q * 16 + r;
            const int off  = rowb * 64 + ((g * 16) ^ (((rowb >> 1) & 3) << 4));
            bf[q] = *reinterpret_cast<const f16x8*>((const char*)&Bb[bbuf][0] + off);
        }
#pragma unroll
        for (int fr = 0; fr < 4; ++fr)
#pragma unroll
            for (int fc = 0; fc < 4; ++fc)
                acc[fr][fc] = __builtin_amdgcn_mfma_f32_16x16x32_f16(
                    af[fr], bf[fc], acc[fr][fc], 0, 0, 0);
    };

    // ---- prologue: B0,B1 in LDS-flight; A0,A1 in reg-flight; write A0.
    float4 pa0, pa1, qa0, qa1;
    gldb(0, 0);
    gldb(1, 1);
    lda(0, pa0, pa1);
    lda(1, qa0, qa1);
    sta(pa0, pa1, 0);          // compiler: vmcnt wait for A0 only (A1 stays in flight)
    SOFT_BAR();

    int bcur = 0;
    for (int t = 0; t < NSTEP; t += 2) {
        // ---- even sub-iter: tile t (Ab[0], Bb[bcur])
        if (t + 2 < NSTEP) {
            gldb(t + 2, bcur == 0 ? 2 : bcur - 1);   // (t+2)%3
            lda(t + 2, pa0, pa1);
        }
        comp(0, bcur);
        sta(qa0, qa1, 1);       // A(t+1); vmcnt(4) -> retires B(t+1) too
        SOFT_BAR();
        const int bn = (bcur == 2) ? 0 : bcur + 1;

        // ---- odd sub-iter: tile t+1 (Ab[1], Bb[bn])
        if (t + 3 < NSTEP) {
            gldb(t + 3, bn == 0 ? 2 : bn - 1);       // (t+3)%3
            lda(t + 3, qa0, qa1);
        }
        comp(1, bn);
        if (t + 2 < NSTEP) sta(pa0, pa1, 0);         // A(t+2)
        SOFT_BAR();
        bcur = (bn == 2) ? 0 : bn + 1;
    }

    // ---- epilogue: partial over this block's 256 cols
    float qv[4], vv[4];
#pragma unroll
    for (int fc = 0; fc < 4; ++fc) {
        const int col = n0 + wc * 64 + fc * 16 + r;
        qv[fc] = query[(size_t)bat * UNITS + col] + b2[col];
        vv[fc] = V[col];
    }
    float ps[4][4];
#pragma unroll
    for (int fr = 0; fr < 4; ++fr)
#pragma unroll
        for (int i = 0; i < 4; ++i) ps[fr][i] = 0.f;
#pragma unroll
    for (int fc = 0; fc < 4; ++fc)
#pragma unroll
        for (int fr = 0; fr < 4; ++fr)
#pragma unroll
            for (int i = 0; i < 4; ++i)
                ps[fr][i] += tanh_fast(acc[fr][fc][i] + qv[fc]) * vv[fc];
#pragma unroll
    for (int off = 1; off < 16; off <<= 1)
#pragma unroll
        for (int fr = 0; fr < 4; ++fr)
#pragma unroll
            for (int i = 0; i < 4; ++i)
                ps[fr][i] += __shfl_xor(ps[fr][i], off, 64);
    if (r == 0)
#pragma unroll
        for (int fr = 0; fr < 4; ++fr)
#pragma unroll
            for (int i = 0; i < 4; ++i)
                sc_part[wc][wr * 64 + fr * 16 + g * 4 + i] = ps[fr][i];
    __syncthreads();
    if (tid < BM)
        psc[(size_t)n_blk * 65536 + row0 + tid] =
            sc_part[0][tid] + sc_part[1][tid] + sc_part[2][tid] + sc_part[3][tid];
}

// ---------------- softmax (merges 2 n-planes; bv dropped: shift-invariant)
__global__ __launch_bounds__(256) void k_softmax(const float* __restrict__ psc,
                                                 float* __restrict__ weights) {
    const int b = blockIdx.x;
    const int tid = threadIdx.x;
    __shared__ float wmax[4], wsum[4];
    float v[8];
    float lm = -1e30f;
#pragma unroll
    for (int i = 0; i < 8; ++i) {
        const size_t idx = (size_t)b * S_LEN + tid + i * 256;
        v[i] = psc[idx] + psc[65536 + idx];
        lm = fmaxf(lm, v[i]);
    }
    for (int off = 32; off; off >>= 1) lm = fmaxf(lm, __shfl_xor(lm, off, 64));
    if ((tid & 63) == 0) wmax[tid >> 6] = lm;
    __syncthreads();
    const float m = fmaxf(fmaxf(wmax[0], wmax[1]), fmaxf(wmax[2], wmax[3]));
    float ls = 0.f;
#pragma unroll
    for (int i = 0; i < 8; ++i) { v[i] = __expf(v[i] - m); ls += v[i]; }
    for (int off = 32; off; off >>= 1) ls += __shfl_xor(ls, off, 64);
    if ((tid & 63) == 0) wsum[tid >> 6] = ls;
    __syncthreads();
    const float inv = 1.f / (wsum[0] + wsum[1] + wsum[2] + wsum[3]);
#pragma unroll
    for (int i = 0; i < 8; ++i)
        weights[(size_t)b * S_LEN + tid + i * 256] = v[i] * inv;
}

// ---------------- context partials
#define SCH 128
#define NCH (S_LEN / SCH)
__global__ __launch_bounds__(256) void k_ctx_part(const float* __restrict__ enc,
                                                  const float* __restrict__ weights,
                                                  float* __restrict__ part) {
    const int b  = blockIdx.x >> 4;
    const int ch = blockIdx.x & 15;
    const int s0 = ch * SCH;
    const int d4 = threadIdx.x * 4;
    __shared__ float wl[SCH];
    if (threadIdx.x < SCH) wl[threadIdx.x] = weights[(size_t)b * S_LEN + s0 + threadIdx.x];
    __syncthreads();
    float4 a = {0.f, 0.f, 0.f, 0.f};
    const float* base = enc + (size_t)b * S_LEN * D_ENC + (size_t)s0 * D_ENC + d4;
#pragma unroll 4
    for (int s = 0; s < SCH; ++s) {
        const float4 e = *reinterpret_cast<const float4*>(base + (size_t)s * D_ENC);
        const float w = wl[s];
        a.x += w * e.x; a.y += w * e.y; a.z += w * e.z; a.w += w * e.w;
    }
    *reinterpret_cast<float4*>(&part[(size_t)blockIdx.x * D_ENC + d4]) = a;
}

__global__ __launch_bounds__(256) void k_ctx_combine(const float* __restrict__ part,
                                                     float* __restrict__ ctx) {
    const int idx = blockIdx.x * 256 + threadIdx.x;
    const int b = idx >> 10;
    const int d = idx & 1023;
    float s = 0.f;
#pragma unroll
    for (int c = 0; c < NCH; ++c) s += part[(size_t)(b * NCH + c) * D_ENC + d];
    ctx[idx] = s;
}

extern "C" void kernel_launch(void* const* d_in, const int* in_sizes, int n_in,
                              void* d_out, int out_size, void* d_ws, size_t ws_size,
                              hipStream_t stream) {
    const float* dec = (const float*)d_in[0];
    const float* enc = (const float*)d_in[1];
    const float* W1  = (const float*)d_in[2];
    const float* b1  = (const float*)d_in[3];
    const float* W2  = (const float*)d_in[4];
    const float* b2  = (const float*)d_in[5];
    const float* V   = (const float*)d_in[6];
    // bv unused: softmax shift-invariant

    float* out = (float*)d_out;
    float* out_ctx = out;
    float* out_w   = out + BATCH * D_ENC;

    char* ws = (char*)d_ws;
    _Float16* W2h = (_Float16*)(ws);                        // 1 MB
    float* query  = (float*)(ws + (1 << 20));               // 64 KB
    float* psc    = (float*)(ws + (1 << 20) + (1 << 16));   // 512 KB (2 planes)
    float* part   = (float*)(ws + (1 << 20) + (1 << 16) + (1 << 19)); // 2 MB

    k_prep_w2<<<dim3(D_DEC / 32, UNITS / 32), dim3(32, 8), 0, stream>>>(W2, W2h);
    k_query<<<UNITS / 32, 1024, 0, stream>>>(dec, W1, b1, query);
    k_scores<<<(BATCH * S_LEN) / BM * 2, 512, 0, stream>>>(enc, W2h, query, b2, V, psc);
    k_softmax<<<BATCH, 256, 0, stream>>>(psc, out_w);
    k_ctx_part<<<BATCH * NCH, 256, 0, stream>>>(enc, out_w, part);
    k_ctx_combine<<<(BATCH * D_ENC) / 256, 256, 0, stream>>>(part, out_ctx);
}